// Round 1
// baseline (403.981 us; speedup 1.0000x reference)
//
#include <hip/hip_runtime.h>
#include <hip/hip_bf16.h>
#include <math.h>

#define NB 32          // batch
#define TLEN 160000    // samples per batch
#define KFFT 1024      // n_fft
#define MWIN 800       // win_length
#define HOP 600
#define NBINS 256
#define TT 267         // n frames: 1 + (160000+1024-1024)/600
#define LMAX 13
#define LMIN 3

__device__ __forceinline__ unsigned f2key(float f) {
    unsigned b = __float_as_uint(f);
    return (b & 0x80000000u) ? ~b : (b | 0x80000000u);
}

// ---------------------------------------------------------------- twiddles
__global__ void twiddle_init_kernel(float2* __restrict__ tw) {
    int j = blockIdx.x * blockDim.x + threadIdx.x;
    if (j < 512) {
        double ang = -2.0 * 3.14159265358979323846 * (double)j / 1024.0;
        tw[j] = make_float2((float)cos(ang), (float)sin(ang));
    }
}

// ---------------------------------------------------------------- STFT power
// one block per (frame, batch); 256 threads; 1024-pt radix-2 DIT FFT in LDS
__global__ __launch_bounds__(256) void stft_power_kernel(
        const float* __restrict__ y, const float2* __restrict__ twg,
        float* __restrict__ Y) {
    __shared__ float re[1024];
    __shared__ float im[1024];
    __shared__ float twc[512];
    __shared__ float tws[512];

    const int f = blockIdx.x;   // frame
    const int b = blockIdx.y;   // batch
    const int tid = threadIdx.x;

    for (int j = tid; j < 512; j += 256) {
        float2 t = twg[j];
        twc[j] = t.x; tws[j] = t.y;
    }

    const float* yb = y + (size_t)b * TLEN;
    // load windowed samples in bit-reversed positions
    for (int i = tid; i < 1024; i += 256) {
        int n = (int)(__brev((unsigned)i) >> 22);   // 10-bit reverse
        float v = 0.0f;
        if (n >= 112 && n < 912) {                  // centered 800-tap hann
            int pos = f * HOP + n - 512;            // reflect pad K/2 = 512
            if (pos < 0) pos = -pos;
            else if (pos >= TLEN) pos = 2 * TLEN - 2 - pos;
            float nf = (float)(n - 112);
            float arg = (6.2831855f * nf) / 800.0f; // matches jnp f32 order
            float w = 0.5f - 0.5f * cosf(arg);
            v = yb[pos] * w;
        }
        re[i] = v;
        im[i] = 0.0f;
    }
    __syncthreads();

    // 10 DIT stages; butterflies within a stage are disjoint -> no intra-stage sync
    for (int s = 0; s < 10; ++s) {
        const int half = 1 << s;
        for (int k = tid; k < 512; k += 256) {
            int j  = k & (half - 1);
            int i0 = ((k >> s) << (s + 1)) | j;
            int i1 = i0 + half;
            int tj = j << (9 - s);
            float c = twc[tj], sn = tws[tj];
            float ar = re[i0], ai = im[i0];
            float br = re[i1], bi = im[i1];
            float tr = br * c - bi * sn;
            float ti = br * sn + bi * c;
            re[i0] = ar + tr; im[i0] = ai + ti;
            re[i1] = ar - tr; im[i1] = ai - ti;
        }
        __syncthreads();
    }

    // bins 0..255, layout Y[b][bin][frame]
    float pr = re[tid], pi = im[tid];
    Y[((size_t)b * NBINS + tid) * TT + f] = pr * pr + pi * pi;
}

// ---------------------------------------------------------------- per-subband
// one block per (b,f): run detection, EDC, regression slope, rt60 key.
// Writes uint keys IN PLACE over the spectrogram row (row staged to LDS first).
__global__ __launch_bounds__(256) void subband_kernel(float* Y) {
    __shared__ float ys[TT];
    __shared__ short runs[TT];
    __shared__ int maxrun_s;

    const int tid = threadIdx.x;
    float* row = Y + (size_t)blockIdx.x * TT;

    for (int t = tid; t < TT; t += 256) ys[t] = row[t];
    __syncthreads();

    if (tid == 0) {
        int r = 0;
        runs[TT - 1] = 0;
        int mr = 0;
        for (int t = TT - 2; t >= 0; --t) {
            r = (ys[t + 1] < ys[t]) ? (r + 1) : 0;
            runs[t] = (short)r;
            if (r > mr) mr = r;
        }
        maxrun_s = mr;
    }
    __syncthreads();

    const int maxrun = maxrun_s;
    unsigned* krow = (unsigned*)row;

    if (maxrun < 2) {   // has_any == false: nothing valid in this subband
        for (int t = tid; t < TT; t += 256) krow[t] = 0xFFFFFFFFu;
        return;
    }

    const int L = min(LMAX, maxrun + 1);   // chosen window length

    // xm, den exactly as the reference computes them (f32, ascending j)
    float sumx = 0.0f;
    #pragma unroll
    for (int j = 0; j < LMAX; ++j) if (j < L) sumx += (float)j;
    const float xm = sumx / (float)L;
    float den = 0.0f;
    #pragma unroll
    for (int j = 0; j < LMAX; ++j) if (j < L) { float xc = (float)j - xm; den += xc * xc; }

    for (int t = tid; t < TT; t += 256) {
        unsigned key = 0xFFFFFFFFu;
        if ((int)runs[t] >= L - 1) {   // start_mask (t+L<=T is implied by run length)
            // suffix sums, accumulated high-index -> low, matching reversed cumsum
            float edc[LMAX];
            float s = 0.0f;
            #pragma unroll
            for (int j = LMAX - 1; j >= 0; --j) {
                if (j < L) s += ys[t + j];
                edc[j] = s;
            }
            float db0 = 10.0f * log10f(fmaxf(edc[0], 1e-10f));
            float scl[LMAX];
            float s1 = 0.0f;
            float last = 0.0f;
            #pragma unroll
            for (int j = 0; j < LMAX; ++j) {
                if (j < L) {
                    float db = 10.0f * log10f(fmaxf(edc[j], 1e-10f));
                    float sc = db - db0;
                    scl[j] = sc;
                    s1 += sc;
                    if (j == L - 1) last = sc;
                }
            }
            const float ym = s1 / (float)L;
            float num = 0.0f;
            #pragma unroll
            for (int j = 0; j < LMAX; ++j)
                if (j < L) num += ((float)j - xm) * (scl[j] - ym);
            const float slope = num / den;
            if (last < -10.0f) {       // selected
                float rt60 = (-60.0f / slope) * 0.0375f;   // * HOP/FS
                key = f2key(rt60);
            }
        }
        krow[t] = key;
    }
}

// ---------------------------------------------------------------- median select
// one block per batch: exact k-th smallest via 4-pass MSB radix select
__global__ __launch_bounds__(256) void median_kernel(
        const unsigned* __restrict__ keys, const float* __restrict__ coeffs,
        float* __restrict__ out) {
    __shared__ int hist[256];
    __shared__ int nvalid_s;
    __shared__ int kk_s;
    __shared__ unsigned prefix_s;

    const int b = blockIdx.x;
    const int tid = threadIdx.x;
    const int NTOT = NBINS * TT;   // 68352 candidates per batch
    const unsigned* kb = keys + (size_t)b * NTOT;

    unsigned prefix = 0, pmask = 0;
    for (int pass = 0; pass < 4; ++pass) {
        const int shift = 24 - 8 * pass;
        hist[tid] = 0;
        if (tid == 0 && pass == 0) nvalid_s = 0;
        __syncthreads();

        int vloc = 0;
        for (int i = tid; i < NTOT; i += 256) {
            unsigned k = kb[i];
            if (pass == 0) vloc += (k != 0xFFFFFFFFu) ? 1 : 0;
            if ((k & pmask) == prefix)
                atomicAdd(&hist[(k >> shift) & 255], 1);
        }
        if (pass == 0) atomicAdd(&nvalid_s, vloc);
        __syncthreads();

        if (tid == 0) {
            int kk = (pass == 0)
                         ? ((nvalid_s > 0) ? (nvalid_s - 1) / 2 : 0)
                         : kk_s;
            int cum = 0, sel = 255;
            for (int i = 0; i < 256; ++i) {
                int h = hist[i];
                if (kk < cum + h) { sel = i; kk -= cum; break; }
                cum += h;
            }
            kk_s = kk;
            prefix_s = prefix | ((unsigned)sel << shift);
        }
        __syncthreads();
        prefix = prefix_s;
        pmask |= (0xFFu << shift);
        __syncthreads();
    }

    if (tid == 0) {
        const int nvalid = nvalid_s;
        unsigned bits = (prefix & 0x80000000u) ? (prefix & 0x7FFFFFFFu) : ~prefix;
        float med = __uint_as_float(bits);
        float o = (nvalid > 0) ? (coeffs[0] + coeffs[1] * med) : 0.5f;
        o = fmaxf(o, 0.01f);
        out[b] = o;
    }
}

// ----------------------------------------------------------------
extern "C" void kernel_launch(void* const* d_in, const int* in_sizes, int n_in,
                              void* d_out, int out_size, void* d_ws, size_t ws_size,
                              hipStream_t stream) {
    const float* y = (const float*)d_in[0];
    const float* coeffs = (const float*)d_in[1];
    float* out = (float*)d_out;

    // ws layout: [ Y/keys : NB*NBINS*TT floats ][ twiddles : 512 float2 ]
    float* Y = (float*)d_ws;
    size_t ybytes = (size_t)NB * NBINS * TT * sizeof(float);   // 8,749,056 B
    float2* tw = (float2*)((char*)d_ws + ybytes);

    twiddle_init_kernel<<<2, 256, 0, stream>>>(tw);
    stft_power_kernel<<<dim3(TT, NB), 256, 0, stream>>>(y, tw, Y);
    subband_kernel<<<NB * NBINS, 256, 0, stream>>>(Y);
    median_kernel<<<NB, 256, 0, stream>>>((const unsigned*)Y, coeffs, out);
}

// Round 2
// 296.060 us; speedup vs baseline: 1.3645x; 1.3645x over previous
//
#include <hip/hip_runtime.h>
#include <hip/hip_bf16.h>
#include <math.h>

#define NB 32          // batch
#define TLEN 160000    // samples per batch
#define KFFT 1024      // n_fft
#define MWIN 800       // win_length
#define HOP 600
#define NBINS 256
#define TT 267         // frames: 1 + (160000+1024-1024)/600
#define NTOT (NBINS * TT)   // 68352 candidates per batch
#define LMAX 13
#define LMIN 3

__device__ __forceinline__ unsigned f2key(float f) {
    unsigned b = __float_as_uint(f);
    return (b & 0x80000000u) ? ~b : (b | 0x80000000u);
}

// ---------------------------------------------------------------- twiddles
__global__ void twiddle_init_kernel(float2* __restrict__ tw) {
    int j = blockIdx.x * blockDim.x + threadIdx.x;
    if (j < 512) {
        double ang = -2.0 * 3.14159265358979323846 * (double)j / 1024.0;
        tw[j] = make_float2((float)cos(ang), (float)sin(ang));
    }
}

// ---------------------------------------------------------------- STFT power
// one block per (frame, batch); 256 threads; 1024-pt radix-2 DIT FFT in LDS
__global__ __launch_bounds__(256) void stft_power_kernel(
        const float* __restrict__ y, const float2* __restrict__ twg,
        float* __restrict__ Y) {
    __shared__ float re[1024];
    __shared__ float im[1024];
    __shared__ float twc[512];
    __shared__ float tws[512];

    const int f = blockIdx.x;   // frame
    const int b = blockIdx.y;   // batch
    const int tid = threadIdx.x;

    for (int j = tid; j < 512; j += 256) {
        float2 t = twg[j];
        twc[j] = t.x; tws[j] = t.y;
    }

    const float* yb = y + (size_t)b * TLEN;
    // load windowed samples in bit-reversed positions
    for (int i = tid; i < 1024; i += 256) {
        int n = (int)(__brev((unsigned)i) >> 22);   // 10-bit reverse
        float v = 0.0f;
        if (n >= 112 && n < 912) {                  // centered 800-tap hann
            int pos = f * HOP + n - 512;            // reflect pad K/2 = 512
            if (pos < 0) pos = -pos;
            else if (pos >= TLEN) pos = 2 * TLEN - 2 - pos;
            float nf = (float)(n - 112);
            float arg = (6.2831855f * nf) / 800.0f;
            float w = 0.5f - 0.5f * cosf(arg);
            v = yb[pos] * w;
        }
        re[i] = v;
        im[i] = 0.0f;
    }
    __syncthreads();

    for (int s = 0; s < 10; ++s) {
        const int half = 1 << s;
        for (int k = tid; k < 512; k += 256) {
            int j  = k & (half - 1);
            int i0 = ((k >> s) << (s + 1)) | j;
            int i1 = i0 + half;
            int tj = j << (9 - s);
            float c = twc[tj], sn = tws[tj];
            float ar = re[i0], ai = im[i0];
            float br = re[i1], bi = im[i1];
            float tr = br * c - bi * sn;
            float ti = br * sn + bi * c;
            re[i0] = ar + tr; im[i0] = ai + ti;
            re[i1] = ar - tr; im[i1] = ai - ti;
        }
        __syncthreads();
    }

    float pr = re[tid], pi = im[tid];
    Y[((size_t)b * NBINS + tid) * TT + f] = pr * pr + pi * pi;
}

// ---------------------------------------------------------------- per-subband
// one block per (b,f): parallel run detection (suffix-min scan), EDC,
// regression slope, rt60 key. Writes uint keys in place over the spectrogram
// row AND accumulates a per-batch 65536-bin histogram of key>>16 + nvalid.
__global__ __launch_bounds__(256) void subband_kernel(
        float* __restrict__ Y, unsigned* __restrict__ hist,
        int* __restrict__ nvalid) {
    __shared__ float ys[TT];
    __shared__ int nz[TT];
    __shared__ int red[256];

    const int tid = threadIdx.x;
    const int b = blockIdx.x >> 8;          // 256 subbands per batch
    float* row = Y + (size_t)blockIdx.x * TT;

    for (int t = tid; t < TT; t += 256) ys[t] = row[t];
    __syncthreads();

    // e[t] = t where the decreasing chain breaks (sentinel at TT-1)
    for (int t = tid; t < TT; t += 256) {
        int e;
        if (t == TT - 1) e = TT - 1;
        else e = (ys[t + 1] < ys[t]) ? 0x7FFFFFFF : t;
        nz[t] = e;
    }
    __syncthreads();

    // Hillis-Steele suffix-min: nz[t] = min(e[t..TT-1])
    for (int step = 1; step < TT; step <<= 1) {
        int t0 = tid, t1 = tid + 256;
        int v0 = min(nz[t0], nz[min(t0 + step, TT - 1)]);
        int v1 = 0;
        bool h1 = (t1 < TT);
        if (h1) v1 = min(nz[t1], nz[min(t1 + step, TT - 1)]);
        __syncthreads();
        nz[t0] = v0;
        if (h1) nz[t1] = v1;
        __syncthreads();
    }
    // runs[t] = nz[t] - t  (length of strictly-decreasing step run from t)

    int lmax = nz[tid] - tid;
    if (tid + 256 < TT) lmax = max(lmax, nz[tid + 256] - (tid + 256));
    red[tid] = lmax;
    __syncthreads();
    for (int s = 128; s > 0; s >>= 1) {
        if (tid < s) red[tid] = max(red[tid], red[tid + s]);
        __syncthreads();
    }
    const int maxrun = red[0];
    __syncthreads();

    unsigned* krow = (unsigned*)row;
    if (maxrun < 2) {   // has_any == false
        for (int t = tid; t < TT; t += 256) krow[t] = 0xFFFFFFFFu;
        return;
    }

    const int L = min(LMAX, maxrun + 1);

    float sumx = 0.0f;
    #pragma unroll
    for (int j = 0; j < LMAX; ++j) if (j < L) sumx += (float)j;
    const float xm = sumx / (float)L;
    float den = 0.0f;
    #pragma unroll
    for (int j = 0; j < LMAX; ++j) if (j < L) { float xc = (float)j - xm; den += xc * xc; }

    unsigned* hb = hist + ((size_t)b << 16);
    int myvalid = 0;

    for (int t = tid; t < TT; t += 256) {
        unsigned key = 0xFFFFFFFFu;
        if (nz[t] - t >= L - 1) {
            float edc[LMAX];
            float s = 0.0f;
            #pragma unroll
            for (int j = LMAX - 1; j >= 0; --j) {
                if (j < L) s += ys[t + j];
                edc[j] = s;
            }
            float db0 = 10.0f * log10f(fmaxf(edc[0], 1e-10f));
            float scl[LMAX];
            float s1 = 0.0f;
            float last = 0.0f;
            #pragma unroll
            for (int j = 0; j < LMAX; ++j) {
                if (j < L) {
                    float db = 10.0f * log10f(fmaxf(edc[j], 1e-10f));
                    float sc = db - db0;
                    scl[j] = sc;
                    s1 += sc;
                    if (j == L - 1) last = sc;
                }
            }
            const float ym = s1 / (float)L;
            float num = 0.0f;
            #pragma unroll
            for (int j = 0; j < LMAX; ++j)
                if (j < L) num += ((float)j - xm) * (scl[j] - ym);
            const float slope = num / den;
            if (last < -10.0f) {
                float rt60 = (-60.0f / slope) * 0.0375f;
                key = f2key(rt60);
            }
        }
        krow[t] = key;
        if (key != 0xFFFFFFFFu) {
            ++myvalid;
            atomicAdd(&hb[key >> 16], 1u);
        }
    }

    red[tid] = myvalid;
    __syncthreads();
    for (int s = 128; s > 0; s >>= 1) {
        if (tid < s) red[tid] += red[tid + s];
        __syncthreads();
    }
    if (tid == 0 && red[0] > 0) atomicAdd(&nvalid[b], red[0]);
}

// ---------------------------------------------------------------- hi select
// one block per batch: scan 65536-bin hist, find 16-bit prefix holding the
// kk=(nvalid-1)/2 -th valid key; store prefix + residual rank.
__global__ __launch_bounds__(256) void select_hi_kernel(
        const unsigned* __restrict__ hist, const int* __restrict__ nvalid,
        int* __restrict__ prefix, int* __restrict__ kkout) {
    __shared__ unsigned tsum[256];
    __shared__ int sel_thread;
    __shared__ unsigned before;

    const int b = blockIdx.x;
    const int tid = threadIdx.x;
    const unsigned* h = hist + ((size_t)b << 16);

    unsigned s = 0;
    const uint4* h4 = (const uint4*)(h + tid * 256);
    #pragma unroll 4
    for (int i = 0; i < 64; ++i) { uint4 v = h4[i]; s += v.x + v.y + v.z + v.w; }
    tsum[tid] = s;
    __syncthreads();

    if (tid == 0) {
        int nv = nvalid[b];
        unsigned kk = (nv > 0) ? (unsigned)((nv - 1) / 2) : 0u;
        unsigned cum = 0; int st = 255; unsigned bef = 0;
        for (int i = 0; i < 256; ++i) {
            unsigned hh = tsum[i];
            if (kk < cum + hh) { st = i; bef = cum; break; }
            cum += hh;
        }
        sel_thread = st; before = bef;
    }
    __syncthreads();

    if (tid == sel_thread) {
        int nv = nvalid[b];
        int kk = ((nv > 0) ? (nv - 1) / 2 : 0) - (int)before;
        unsigned cum = 0; int sel = 255;
        for (int i = 0; i < 256; ++i) {
            unsigned hh = h[tid * 256 + i];
            if ((unsigned)kk < cum + hh) { sel = i; kk -= (int)cum; break; }
            cum += hh;
        }
        prefix[b] = (tid << 8) | sel;
        kkout[b] = kk;
    }
}

// ---------------------------------------------------------------- low hist
// full-grid re-scan of keys: histogram low 16 bits of prefix-matching keys
__global__ __launch_bounds__(256) void histlo_kernel(
        const unsigned* __restrict__ keys, const int* __restrict__ prefix,
        unsigned* __restrict__ histB) {
    const int b = blockIdx.y;
    const unsigned pfx = (unsigned)prefix[b];
    const unsigned* kb = keys + (size_t)b * NTOT;
    unsigned* h = histB + ((size_t)b << 16);
    for (int i = blockIdx.x * 256 + threadIdx.x; i < NTOT; i += gridDim.x * 256) {
        unsigned k = kb[i];
        if ((k >> 16) == pfx) atomicAdd(&h[k & 0xFFFFu], 1u);
    }
}

// ---------------------------------------------------------------- lo select
__global__ __launch_bounds__(256) void select_lo_kernel(
        const unsigned* __restrict__ histB, const int* __restrict__ nvalid,
        const int* __restrict__ prefix, const int* __restrict__ kkin,
        const float* __restrict__ coeffs, float* __restrict__ out) {
    __shared__ unsigned tsum[256];
    __shared__ int sel_thread;
    __shared__ unsigned before;

    const int b = blockIdx.x;
    const int tid = threadIdx.x;
    const unsigned* h = histB + ((size_t)b << 16);

    unsigned s = 0;
    const uint4* h4 = (const uint4*)(h + tid * 256);
    #pragma unroll 4
    for (int i = 0; i < 64; ++i) { uint4 v = h4[i]; s += v.x + v.y + v.z + v.w; }
    tsum[tid] = s;
    __syncthreads();

    if (tid == 0) {
        unsigned kk = (unsigned)kkin[b];
        unsigned cum = 0; int st = 255; unsigned bef = 0;
        for (int i = 0; i < 256; ++i) {
            unsigned hh = tsum[i];
            if (kk < cum + hh) { st = i; bef = cum; break; }
            cum += hh;
        }
        sel_thread = st; before = bef;
    }
    __syncthreads();

    if (tid == sel_thread) {
        int kk = kkin[b] - (int)before;
        unsigned cum = 0; int sel = 255;
        for (int i = 0; i < 256; ++i) {
            unsigned hh = h[tid * 256 + i];
            if ((unsigned)kk < cum + hh) { sel = i; break; }
            cum += hh;
        }
        unsigned kx = ((unsigned)prefix[b] << 16) | (unsigned)((tid << 8) | sel);
        unsigned fb = (kx & 0x80000000u) ? (kx & 0x7FFFFFFFu) : ~kx;
        float med = __uint_as_float(fb);
        float o = (nvalid[b] > 0) ? (coeffs[0] + coeffs[1] * med) : 0.5f;
        out[b] = fmaxf(o, 0.01f);
    }
}

// ----------------------------------------------------------------
extern "C" void kernel_launch(void* const* d_in, const int* in_sizes, int n_in,
                              void* d_out, int out_size, void* d_ws, size_t ws_size,
                              hipStream_t stream) {
    const float* y = (const float*)d_in[0];
    const float* coeffs = (const float*)d_in[1];
    float* out = (float*)d_out;

    // ws layout:
    //   [0]                 Y / keys : NB*NBINS*TT floats = 8,749,056 B
    //   [YB]                hist     : NB*65536 uint      = 8,388,608 B (reused hi->lo)
    //   [YB+HB]             scratch  : nvalid[NB], prefix[NB], kk[NB]
    //   [YB+HB+512]         twiddles : 512 float2
    const size_t YB = (size_t)NB * NBINS * TT * sizeof(float);
    const size_t HB = (size_t)NB * 65536 * sizeof(unsigned);
    char* base = (char*)d_ws;
    float* Y = (float*)base;
    unsigned* hist = (unsigned*)(base + YB);
    int* nvalid = (int*)(base + YB + HB);
    int* prefix = nvalid + NB;
    int* kk = prefix + NB;
    float2* tw = (float2*)(base + YB + HB + 512);

    hipMemsetAsync(hist, 0, HB + 512, stream);   // hist + scratch
    twiddle_init_kernel<<<2, 256, 0, stream>>>(tw);
    stft_power_kernel<<<dim3(TT, NB), 256, 0, stream>>>(y, tw, Y);
    subband_kernel<<<NB * NBINS, 256, 0, stream>>>(Y, hist, nvalid);
    select_hi_kernel<<<NB, 256, 0, stream>>>(hist, nvalid, prefix, kk);
    hipMemsetAsync(hist, 0, HB, stream);         // reuse as low-16 hist
    histlo_kernel<<<dim3(32, NB), 256, 0, stream>>>((const unsigned*)Y, prefix, hist);
    select_lo_kernel<<<NB, 256, 0, stream>>>(hist, nvalid, prefix, kk, coeffs, out);
}